// Round 21
// baseline (80.262 us; speedup 1.0000x reference)
//
#include <hip/hip_runtime.h>
#include <math.h>

#define BATCH 16
#define SEQ 64
#define NKEY 196
#define HIDDEN 1024
#define ATT_FEAT 2048
#define EMBED 512
#define MPAD 3200          // feats rows padded to multiple of 128

using half8    = __attribute__((ext_vector_type(8))) _Float16;
using half4    = __attribute__((ext_vector_type(4))) _Float16;
using f32x4    = __attribute__((ext_vector_type(4))) float;
using f32x16   = __attribute__((ext_vector_type(16))) float;
using float4v  = __attribute__((ext_vector_type(4))) float;

#define KCONST (-2.8853900817779268f)   // -2*log2(e)
#define LOG2E  (1.4426950408889634f)

// async global->LDS, 16B per lane; dest = uniform base + lane*16
__device__ __forceinline__ void gl_lds16(const _Float16* g, _Float16* l) {
    __builtin_amdgcn_global_load_lds(
        (const __attribute__((address_space(1))) unsigned int*)g,
        (__attribute__((address_space(3))) unsigned int*)l, 16, 0, 0);
}

// ---------------------------------------------------------------------------
// Tiled f16 images: per (row-tile 128, k-tile 32): [s(2)][kh(2)][row(128)][8]
// ---------------------------------------------------------------------------
__device__ inline void prep_a128(
    const float* __restrict__ A, _Float16* __restrict__ T,
    int K, int Mreal, int tm, int tk, int t)
{
    const int r  = t >> 1;
    const int hf = t & 1;
    const int grow = tm * 128 + r;
    float f[32];
    if (grow < Mreal) {
        const float* src = A + (size_t)grow * K + tk * 64 + hf * 32;
        #pragma unroll
        for (int q = 0; q < 8; ++q) {
            float4v v = *(const float4v*)(src + q * 4);
            f[q*4+0] = v.x; f[q*4+1] = v.y; f[q*4+2] = v.z; f[q*4+3] = v.w;
        }
    } else {
        #pragma unroll
        for (int j = 0; j < 32; ++j) f[j] = 0.f;
    }
    const int tkk = tk * 2 + hf;
    const size_t base = ((size_t)tm * (K >> 5) + tkk) * 4096;
    #pragma unroll
    for (int s = 0; s < 2; ++s)
        #pragma unroll
        for (int kh = 0; kh < 2; ++kh) {
            half8 h;
            #pragma unroll
            for (int j = 0; j < 8; ++j)
                h[j] = (_Float16)f[s * 16 + kh * 8 + j];
            *(half8*)(T + base + (size_t)((s * 2 + kh) * 128 + r) * 8) = h;
        }
}

__device__ inline void prep_b128(
    const float* __restrict__ W, _Float16* __restrict__ T,
    int K, int N, int tn, int tk, int t, float (*tile)[129])
{
    {
        const int kr = t >> 2;
        const int nc = (t & 3) * 32;
        const float* src = W + (size_t)(tk * 64 + kr) * N + tn * 128 + nc;
        #pragma unroll
        for (int q = 0; q < 8; ++q) {
            float4v v = *(const float4v*)(src + q * 4);
            tile[kr][nc + q*4 + 0] = v.x; tile[kr][nc + q*4 + 1] = v.y;
            tile[kr][nc + q*4 + 2] = v.z; tile[kr][nc + q*4 + 3] = v.w;
        }
    }
    __syncthreads();
    {
        const int c  = t >> 1;
        const int hf = t & 1;
        const int tkk = tk * 2 + hf;
        const size_t base = ((size_t)tn * (K >> 5) + tkk) * 4096;
        #pragma unroll
        for (int s = 0; s < 2; ++s)
            #pragma unroll
            for (int kh = 0; kh < 2; ++kh) {
                half8 h;
                #pragma unroll
                for (int j = 0; j < 8; ++j)
                    h[j] = (_Float16)tile[hf * 32 + s * 16 + kh * 8 + j][c];
                *(half8*)(T + base + (size_t)((s * 2 + kh) * 128 + c) * 8) = h;
            }
    }
}

// feats[b] [196][2048] f32 -> FT[b] [2048 f-rows][224 n-k] f16 tiled image.
__device__ inline void prep_bT(
    const float* __restrict__ Wb, _Float16* __restrict__ T,
    int tn, int tk, int t, float (*tile)[129])
{
    {
        const int kr = t >> 2;              // n within 64-tile
        const int nc = (t & 3) * 32;        // f within 128-tile
        const int gn = tk * 64 + kr;
        #pragma unroll
        for (int q = 0; q < 8; ++q) {
            float4v v = {0.f, 0.f, 0.f, 0.f};
            if (gn < NKEY)
                v = *(const float4v*)(Wb + (size_t)gn * ATT_FEAT + tn * 128 + nc + q * 4);
            tile[kr][nc + q*4 + 0] = v.x; tile[kr][nc + q*4 + 1] = v.y;
            tile[kr][nc + q*4 + 2] = v.z; tile[kr][nc + q*4 + 3] = v.w;
        }
    }
    __syncthreads();
    {
        const int c  = t >> 1;              // f-row 0..127
        const int hf = t & 1;
        const int tkk = tk * 2 + hf;        // n-32-tile; valid 0..6
        if (tkk < 7) {
            const size_t base = ((size_t)tn * 7 + tkk) * 4096;
            #pragma unroll
            for (int s = 0; s < 2; ++s)
                #pragma unroll
                for (int kh = 0; kh < 2; ++kh) {
                    half8 h;
                    #pragma unroll
                    for (int j = 0; j < 8; ++j)
                        h[j] = (_Float16)tile[hf * 32 + s * 16 + kh * 8 + j][c];
                    *(half8*)(T + base + (size_t)((s * 2 + kh) * 128 + c) * 8) = h;
                }
        }
    }
}

__global__ __launch_bounds__(256) void uber_prep(
    const float* __restrict__ hidden, const float* __restrict__ feats,
    const float* __restrict__ w_h, const float* __restrict__ w_u,
    _Float16* HA, _Float16* FA, _Float16* HB, _Float16* UB)
{
    __shared__ float tile[64][129];
    const int id = blockIdx.x;
    const int t  = threadIdx.x;
    if (id < 128) {
        prep_a128(hidden, HA, HIDDEN, BATCH * SEQ, id >> 4, id & 15, t);
    } else if (id < 928) {
        const int j = id - 128;
        prep_a128(feats, FA, ATT_FEAT, BATCH * NKEY, j >> 5, j & 31, t);
    } else if (id < 992) {
        const int j = id - 928;
        prep_b128(w_h, HB, HIDDEN, EMBED, j >> 4, j & 15, t, tile);
    } else {
        const int j = id - 992;
        prep_b128(w_u, UB, ATT_FEAT, EMBED, j >> 5, j & 31, t, tile);
    }
}

// ---------------------------------------------------------------------------
// uber GEMM f16 (k-split) + FT co-run. Grid 1488 = 8 XCD x 186 slots:
//   slot idx < 58  -> gemm unit t0 = xcd*58+idx (0..463, R19 distribution)
//   slot idx >= 58 -> FT transpose unit f = xcd*128 + (idx-58) (0..1023)
// gemm: 128x128 tile, 4 waves 2x2, wave 64x64, BK=32, 16 k-steps/block,
// 3-deep LDS buffers (48 KB), counted vmcnt(4); f16 partials, KC-scaled.
// ---------------------------------------------------------------------------
__global__ __launch_bounds__(256) void uber_gemm(
    const _Float16* __restrict__ HA, const _Float16* __restrict__ HB,
    const _Float16* __restrict__ FA, const _Float16* __restrict__ UB,
    const float* __restrict__ feats, const float* __restrict__ bvec,
    _Float16* __restrict__ WhP, _Float16* __restrict__ UvP,
    _Float16* __restrict__ FT)
{
    __shared__ __align__(16) char smem[49152];   // gemm 48 KB / FT 33 KB union

    const int tid = threadIdx.x;
    const int hh  = blockIdx.x;
    const int xcd = hh & 7, idx = hh >> 3;

    if (idx >= 58) {                       // ---- FT prep unit ----
        const int f = xcd * 128 + (idx - 58);
        const int b = f >> 6, rem = f & 63;
        prep_bT(feats + (size_t)b * NKEY * ATT_FEAT,
                FT + (size_t)b * 16 * 7 * 4096, rem >> 2, rem & 3, tid,
                (float(*)[129])smem);
        return;
    }

    const int t0 = xcd * 58 + idx;         // 0..463

    const _Float16 *Aimg, *Bimg;
    const float* bias = nullptr;
    _Float16* C;
    int rt, ct, tk0, aK;
    if (t0 < 400) {            // K2: Uv partials
        const int ks = t0 / 100, rem = t0 % 100;
        rt = rem >> 2; ct = rem & 3;
        Aimg = FA; Bimg = UB;
        aK = ATT_FEAT >> 5; tk0 = ks * 16;
        C = UvP + (size_t)ks * MPAD * EMBED;
        if (ks == 0) bias = bvec;
    } else {                   // K1: Wh partials
        const int v = t0 - 400;
        const int ks = v >> 5, rem = v & 31;
        rt = rem >> 2; ct = rem & 3;
        Aimg = HA; Bimg = HB;
        aK = HIDDEN >> 5; tk0 = ks * 16;
        C = WhP + (size_t)ks * (BATCH * SEQ) * EMBED;
    }

    const int lane = tid & 63, w = tid >> 6;
    const int wr = w >> 1, wc = w & 1;
    const int l31 = lane & 31, kh = lane >> 5;

    const int isB = w >> 1;
    const int whf = w & 1;
    const _Float16* srcMat = isB ? Bimg : Aimg;
    const int majorTile = isB ? ct : rt;
    const _Float16* src0 =
        srcMat + ((size_t)majorTile * aK + tk0) * 4096 + whf * 2048 + lane * 8;

    _Float16* Lp = (_Float16*)smem;        // layout [2][3][4096]

    f32x16 acc[2][2] = {};

    auto stage = [&](int buf, int t) {
        const _Float16* s = src0 + (size_t)t * 4096;
        _Float16* d = Lp + (isB * 3 + buf) * 4096 + whf * 2048 + lane * 8;
        #pragma unroll
        for (int c = 0; c < 4; ++c)
            gl_lds16(s + c * 512, d + c * 512);
    };

    auto compute = [&](int buf) {
        const _Float16* LAb = Lp + buf * 4096;
        const _Float16* LBb = Lp + (3 + buf) * 4096;
        #pragma unroll
        for (int s = 0; s < 2; ++s) {
            const int rb = (s * 2 + kh) * 128;
            half8 a[2], b[2];
            #pragma unroll
            for (int m = 0; m < 2; ++m)
                a[m] = *(const half8*)(LAb + (size_t)(rb + wr * 64 + m * 32 + l31) * 8);
            #pragma unroll
            for (int n = 0; n < 2; ++n)
                b[n] = *(const half8*)(LBb + (size_t)(rb + wc * 64 + n * 32 + l31) * 8);
            __builtin_amdgcn_s_setprio(1);
            #pragma unroll
            for (int m = 0; m < 2; ++m)
                #pragma unroll
                for (int n = 0; n < 2; ++n)
                    acc[m][n] = __builtin_amdgcn_mfma_f32_32x32x16_f16(a[m], b[n], acc[m][n], 0, 0, 0);
            __builtin_amdgcn_s_setprio(0);
        }
    };

    stage(0, 0); stage(1, 1);              // prefetch depth 2
    int cur = 0, nxt = 2;
    #pragma unroll 1
    for (int t = 0; t < 16; ++t) {
        if (t + 1 < 16) asm volatile("s_waitcnt vmcnt(4)" ::: "memory");
        else            asm volatile("s_waitcnt vmcnt(0)" ::: "memory");
        __builtin_amdgcn_s_barrier();
        if (t + 2 < 16) stage(nxt, t + 2);
        __builtin_amdgcn_sched_barrier(0);
        compute(cur);
        __builtin_amdgcn_sched_barrier(0);
        cur = (cur == 2) ? 0 : cur + 1;
        nxt = (nxt == 2) ? 0 : nxt + 1;
    }

    // epilogue: col=lane&31, row=(r&3)+8*(r>>2)+4*kh; scale KC, store f16
    #pragma unroll
    for (int m = 0; m < 2; ++m) {
        const int row0 = rt * 128 + wr * 64 + m * 32;
        #pragma unroll
        for (int n = 0; n < 2; ++n) {
            const int colg = ct * 128 + wc * 64 + n * 32 + l31;
            const float bv = bias ? bias[colg] : 0.f;
            #pragma unroll
            for (int r = 0; r < 16; ++r) {
                const int row = (r & 3) + 8 * (r >> 2) + 4 * kh;
                C[(size_t)(row0 + row) * EMBED + colg] =
                    (_Float16)((acc[m][n][r] + bv) * KCONST);
            }
        }
    }
}

// ---------------------------------------------------------------------------
// scores: partial scores over an e-quarter (128 e), f16 partial inputs.
// Block: 64 s x 16 n x 128 e, 4 waves. Grid 832 (13 n x 4 eq x 16 b).
// ---------------------------------------------------------------------------
__global__ __launch_bounds__(256) void scores4_kernel(
    const _Float16* __restrict__ WhP, const _Float16* __restrict__ UvP,
    const float* __restrict__ wvec, float* __restrict__ scr4)
{
    const int id = blockIdx.x;
    const int n0 = (id % 13) * 16;
    const int eq = (id / 13) & 3;
    const int b  = id / 52;
    const int tid = threadIdx.x;
    const int w    = tid >> 6;
    const int lane = tid & 63;         // = s

    __shared__ float whs[64 * 64];     // swizzled, 16 KB
    __shared__ float uvs[16][64];      // plain (broadcast reads)

    const size_t WHS = (size_t)(BATCH * SEQ) * EMBED;
    const size_t UVS = (size_t)MPAD * EMBED;

    float acc[4] = {};
    char* whsB = (char*)whs;

    for (int ch = 0; ch < 2; ++ch) {
        const int e0 = eq * 128 + ch * 64;
        {
            const int r = tid >> 2;
            const _Float16* Wr = WhP + (size_t)(b * SEQ + r) * EMBED + e0 + (tid & 3) * 16;
            half8 h0 = *(const half8*)(Wr);
            half8 h1 = *(const half8*)(Wr + 8);
            half8 g0 = *(const half8*)(Wr + WHS);
            half8 g1 = *(const half8*)(Wr + WHS + 8);
            float f[16];
            #pragma unroll
            for (int j = 0; j < 8; ++j) {
                f[j]     = (float)h0[j] + (float)g0[j];
                f[8 + j] = (float)h1[j] + (float)g1[j];
            }
            #pragma unroll
            for (int q = 0; q < 4; ++q) {
                const int cc = (tid & 3) * 16 + q * 4;
                float4v v = { f[q*4+0], f[q*4+1], f[q*4+2], f[q*4+3] };
                *(float4v*)(whsB + r * 256 + ((cc * 4) ^ ((r & 15) << 4))) = v;
            }
        }
        {
            const int nl = tid >> 4;
            const int c4 = tid & 15;
            const int nr = (n0 + nl < NKEY) ? (n0 + nl) : (NKEY - 1);
            const _Float16* Ur = UvP + (size_t)(b * NKEY + nr) * EMBED + e0 + c4 * 4;
            half4 u0 = *(const half4*)(Ur);
            half4 u1 = *(const half4*)(Ur + UVS);
            half4 u2 = *(const half4*)(Ur + 2 * UVS);
            half4 u3 = *(const half4*)(Ur + 3 * UVS);
            float4v u;
            u.x = ((float)u0[0] + (float)u1[0]) + ((float)u2[0] + (float)u3[0]);
            u.y = ((float)u0[1] + (float)u1[1]) + ((float)u2[1] + (float)u3[1]);
            u.z = ((float)u0[2] + (float)u1[2]) + ((float)u2[2] + (float)u3[2]);
            u.w = ((float)u0[3] + (float)u1[3]) + ((float)u2[3] + (float)u3[3]);
            *(float4v*)&uvs[nl][c4 * 4] = u;
        }
        __syncthreads();

        #pragma unroll
        for (int ec = 0; ec < 8; ++ec) {
            const int sb = lane * 256;
            float4v wh0 = *(const float4v*)(whsB + sb + ((ec * 32 +  0) ^ ((lane & 15) << 4)));
            float4v wh1 = *(const float4v*)(whsB + sb + ((ec * 32 + 16) ^ ((lane & 15) << 4)));
            float wf[8];
            #pragma unroll
            for (int i = 0; i < 8; ++i) wf[i] = wvec[e0 + ec * 8 + i];
            #pragma unroll
            for (int j = 0; j < 4; ++j) {
                const int nl = w * 4 + j;
                float4v u0 = *(const float4v*)&uvs[nl][ec * 8];
                float4v u1 = *(const float4v*)&uvs[nl][ec * 8 + 4];
                float t0 = __builtin_amdgcn_exp2f(wh0.x + u0.x);
                float t1 = __builtin_amdgcn_exp2f(wh0.y + u0.y);
                float t2 = __builtin_amdgcn_exp2f(wh0.z + u0.z);
                float t3 = __builtin_amdgcn_exp2f(wh0.w + u0.w);
                float t4 = __builtin_amdgcn_exp2f(wh1.x + u1.x);
                float t5 = __builtin_amdgcn_exp2f(wh1.y + u1.y);
                float t6 = __builtin_amdgcn_exp2f(wh1.z + u1.z);
                float t7 = __builtin_amdgcn_exp2f(wh1.w + u1.w);
                float a = acc[j];
                a = fmaf(wf[0], __builtin_amdgcn_rcpf(1.f + t0), a);
                a = fmaf(wf[1], __builtin_amdgcn_rcpf(1.f + t1), a);
                a = fmaf(wf[2], __builtin_amdgcn_rcpf(1.f + t2), a);
                a = fmaf(wf[3], __builtin_amdgcn_rcpf(1.f + t3), a);
                a = fmaf(wf[4], __builtin_amdgcn_rcpf(1.f + t4), a);
                a = fmaf(wf[5], __builtin_amdgcn_rcpf(1.f + t5), a);
                a = fmaf(wf[6], __builtin_amdgcn_rcpf(1.f + t6), a);
                a = fmaf(wf[7], __builtin_amdgcn_rcpf(1.f + t7), a);
                acc[j] = a;
            }
        }
        __syncthreads();
    }

    float* dst = scr4 + ((size_t)eq * (BATCH * SEQ) + b * SEQ + lane) * NKEY;
    #pragma unroll
    for (int j = 0; j < 4; ++j) {
        const int n = n0 + w * 4 + j;
        if (n < NKEY) dst[n] = 2.f * acc[j];
    }
}

// ---------------------------------------------------------------------------
// attn MFMA: block = one b x 128 f x all 64 s. Grid (16 fb, 16 b).
// ---------------------------------------------------------------------------
__global__ __launch_bounds__(256) void attn_mfma(
    const float* __restrict__ scr4, const int* __restrict__ mask,
    const _Float16* __restrict__ FT,
    float* __restrict__ weights_out, float* __restrict__ out)
{
    const int fb = blockIdx.x;
    const int b  = blockIdx.y;
    const int t  = threadIdx.x;
    const int lane = t & 63, w = t >> 6;
    const int wr = w >> 1, wc = w & 1;          // wave: 32 s x 64 f
    const int l31 = lane & 31, khl = lane >> 5;

    __shared__ __align__(16) _Float16 wtL[7 * 4 * 64 * 8];   // 28 KB
    __shared__ __align__(16) _Float16 Lb[3][4096];           // 24 KB

    const _Float16* FTb = FT + (size_t)b * 16 * 7 * 4096 + (size_t)fb * 7 * 4096;

    auto stage = [&](int buf, int kt) {
        const _Float16* s = FTb + (size_t)kt * 4096 + w * 1024 + lane * 8;
        _Float16* d = &Lb[buf][0] + w * 1024 + lane * 8;
        gl_lds16(s, d);
        gl_lds16(s + 512, d + 512);
    };

    stage(0, 0); stage(1, 1);

    // ---- zero wtL (covers n in [196,224)) ----
    #pragma unroll
    for (int i = 0; i < 7; ++i)
        *(half8*)&wtL[(i * 256 + t) * 8] = (half8)(_Float16)0.f;

    asm volatile("s_waitcnt lgkmcnt(0)" ::: "memory");
    __builtin_amdgcn_s_barrier();

    // ---- softmax: row r = t>>2 (64 rows), quad lanes ln = t&3 ----
    {
        const int r  = t >> 2;
        const int ln = t & 3;
        const size_t SCRS = (size_t)(BATCH * SEQ) * NKEY;
        const float* p = scr4 + (size_t)(b * SEQ + r) * NKEY;
        const int* mrow = mask + b * NKEY;
        float v[49];
        float mx = -INFINITY;
        #pragma unroll
        for (int j = 0; j < 49; ++j) {
            const int n = ln + 4 * j;
            float s = (p[n] + p[SCRS + n]) + (p[2 * SCRS + n] + p[3 * SCRS + n]);
            if (mrow[n] == 0) s = -1e9f;
            v[j] = s;
            mx = fmaxf(mx, s);
        }
        mx = fmaxf(mx, __shfl_xor(mx, 1));
        mx = fmaxf(mx, __shfl_xor(mx, 2));
        float sum = 0.f;
        #pragma unroll
        for (int j = 0; j < 49; ++j) {
            v[j] = __builtin_amdgcn_exp2f((v[j] - mx) * LOG2E);
            sum += v[j];
        }
        sum += __shfl_xor(sum, 1);
        sum += __shfl_xor(sum, 2);
        const float inv = __builtin_amdgcn_rcpf(sum);
        float* wrow = weights_out + (size_t)(b * SEQ + r) * NKEY;
        #pragma unroll
        for (int j = 0; j < 49; ++j) {
            const int n = ln + 4 * j;
            const float wv = v[j] * inv;
            if (fb == 0) wrow[n] = wv;
            const int grp = ((n >> 4) & 1) * 2 + ((n >> 3) & 1);
            wtL[(((n >> 5) * 4 + grp) * 64 + r) * 8 + (n & 7)] = (_Float16)wv;
        }
    }
    asm volatile("s_waitcnt lgkmcnt(0)" ::: "memory");

    // ---- MFMA k-loop: 7 steps of 32 n ----
    f32x16 acc[2] = {};
    #pragma unroll 1
    for (int kt = 0; kt < 7; ++kt) {
        if (kt < 6) asm volatile("s_waitcnt vmcnt(2)" ::: "memory");
        else        asm volatile("s_waitcnt vmcnt(0)" ::: "memory");
        __builtin_amdgcn_s_barrier();
        if (kt + 2 < 7) stage((kt + 2) % 3, kt + 2);
        __builtin_amdgcn_sched_barrier(0);
        const int buf = kt % 3;
        #pragma unroll
        for (int ks = 0; ks < 2; ++ks) {
            half8 a = *(const half8*)&wtL[(((kt * 4) + ks * 2 + khl) * 64 + wr * 32 + l31) * 8];
            half8 b0 = *(const half8*)&Lb[buf][((ks * 2 + khl) * 128 + wc * 64 + l31) * 8];
            half8 b1 = *(const half8*)&Lb[buf][((ks * 2 + khl) * 128 + wc * 64 + 32 + l31) * 8];
            acc[0] = __builtin_amdgcn_mfma_f32_32x32x16_f16(a, b0, acc[0], 0, 0, 0);
            acc[1] = __builtin_amdgcn_mfma_f32_32x32x16_f16(a, b1, acc[1], 0, 0, 0);
        }
        __builtin_amdgcn_sched_barrier(0);
    }

    // ---- epilogue: C[s, f] ----
    #pragma unroll
    for (int nf = 0; nf < 2; ++nf) {
        const int f = fb * 128 + wc * 64 + nf * 32 + l31;
        #pragma unroll
        for (int r = 0; r < 16; ++r) {
            const int srow = wr * 32 + (r & 3) + 8 * (r >> 2) + 4 * khl;
            out[(size_t)(b * SEQ + srow) * ATT_FEAT + f] = acc[nf][r];
        }
    }
}

// ---------------------------------------------------------------------------
extern "C" void kernel_launch(void* const* d_in, const int* in_sizes, int n_in,
                              void* d_out, int out_size, void* d_ws, size_t ws_size,
                              hipStream_t stream)
{
    const float* hidden = (const float*)d_in[0];
    const float* feats  = (const float*)d_in[1];
    const int*   mask   = (const int*)  d_in[2];
    const float* w_h    = (const float*)d_in[3];
    const float* w_u    = (const float*)d_in[4];
    const float* bvec   = (const float*)d_in[5];
    const float* wvec   = (const float*)d_in[6];

    float* out         = (float*)d_out;
    float* attn_out    = out;
    float* weights_out = out + (size_t)BATCH * SEQ * ATT_FEAT;

    // workspace layout (~52 MB)
    _Float16* WhP = (_Float16*)d_ws;                             // 2 x 1024x512 f16
    _Float16* UvP = WhP + (size_t)2 * BATCH * SEQ * EMBED;       // 4 x 3200x512 f16
    float*    scr4 = (float*)(UvP + (size_t)4 * MPAD * EMBED);   // 4 x 1024x196 f32
    _Float16* FA = (_Float16*)(scr4 + (size_t)4 * BATCH * SEQ * NKEY);
    _Float16* HA = FA + (size_t)MPAD * ATT_FEAT;
    _Float16* UB = HA + (size_t)BATCH * SEQ * HIDDEN;
    _Float16* HB = UB + (size_t)EMBED * ATT_FEAT;
    _Float16* FT = HB + (size_t)EMBED * HIDDEN;                  // 16b x 16tn x 7 x 4096

    // 1) GEMM-image preps (1120 blocks)
    uber_prep<<<dim3(1120), 256, 0, stream>>>(
        hidden, feats, w_h, w_u, HA, FA, HB, UB);

    // 2) both GEMMs k-split (464 units) + FT transpose (1024 units) co-run
    uber_gemm<<<dim3(1488), 256, 0, stream>>>(
        HA, HB, FA, UB, feats, bvec, WhP, UvP, FT);

    // 3) partial scores (832 blocks, lean LDS)
    scores4_kernel<<<dim3(832), 256, 0, stream>>>(
        WhP, UvP, wvec, scr4);

    // 4) softmax + weights write + MFMA attn
    attn_mfma<<<dim3(16, 16), 256, 0, stream>>>(
        scr4, mask, FT, weights_out, attn_out);
}

// Round 22
// 77.008 us; speedup vs baseline: 1.0423x; 1.0423x over previous
//
#include <hip/hip_runtime.h>
#include <math.h>

#define BATCH 16
#define SEQ 64
#define NKEY 196
#define HIDDEN 1024
#define ATT_FEAT 2048
#define EMBED 512
#define MPAD 3200          // feats rows padded to multiple of 128

using half8    = __attribute__((ext_vector_type(8))) _Float16;
using half4    = __attribute__((ext_vector_type(4))) _Float16;
using f32x4    = __attribute__((ext_vector_type(4))) float;
using f32x16   = __attribute__((ext_vector_type(16))) float;
using float4v  = __attribute__((ext_vector_type(4))) float;

#define KCONST (-2.8853900817779268f)   // -2*log2(e)
#define LOG2E  (1.4426950408889634f)

// async global->LDS, 16B per lane; dest = uniform base + lane*16
__device__ __forceinline__ void gl_lds16(const _Float16* g, _Float16* l) {
    __builtin_amdgcn_global_load_lds(
        (const __attribute__((address_space(1))) unsigned int*)g,
        (__attribute__((address_space(3))) unsigned int*)l, 16, 0, 0);
}

// ---------------------------------------------------------------------------
// Tiled f16 images: per (row-tile 128, k-tile 32): [s(2)][kh(2)][row(128)][8]
// ---------------------------------------------------------------------------
__device__ inline void prep_a128(
    const float* __restrict__ A, _Float16* __restrict__ T,
    int K, int Mreal, int tm, int tk, int t)
{
    const int r  = t >> 1;
    const int hf = t & 1;
    const int grow = tm * 128 + r;
    float f[32];
    if (grow < Mreal) {
        const float* src = A + (size_t)grow * K + tk * 64 + hf * 32;
        #pragma unroll
        for (int q = 0; q < 8; ++q) {
            float4v v = *(const float4v*)(src + q * 4);
            f[q*4+0] = v.x; f[q*4+1] = v.y; f[q*4+2] = v.z; f[q*4+3] = v.w;
        }
    } else {
        #pragma unroll
        for (int j = 0; j < 32; ++j) f[j] = 0.f;
    }
    const int tkk = tk * 2 + hf;
    const size_t base = ((size_t)tm * (K >> 5) + tkk) * 4096;
    #pragma unroll
    for (int s = 0; s < 2; ++s)
        #pragma unroll
        for (int kh = 0; kh < 2; ++kh) {
            half8 h;
            #pragma unroll
            for (int j = 0; j < 8; ++j)
                h[j] = (_Float16)f[s * 16 + kh * 8 + j];
            *(half8*)(T + base + (size_t)((s * 2 + kh) * 128 + r) * 8) = h;
        }
}

__device__ inline void prep_b128(
    const float* __restrict__ W, _Float16* __restrict__ T,
    int K, int N, int tn, int tk, int t, float (*tile)[129])
{
    {
        const int kr = t >> 2;
        const int nc = (t & 3) * 32;
        const float* src = W + (size_t)(tk * 64 + kr) * N + tn * 128 + nc;
        #pragma unroll
        for (int q = 0; q < 8; ++q) {
            float4v v = *(const float4v*)(src + q * 4);
            tile[kr][nc + q*4 + 0] = v.x; tile[kr][nc + q*4 + 1] = v.y;
            tile[kr][nc + q*4 + 2] = v.z; tile[kr][nc + q*4 + 3] = v.w;
        }
    }
    __syncthreads();
    {
        const int c  = t >> 1;
        const int hf = t & 1;
        const int tkk = tk * 2 + hf;
        const size_t base = ((size_t)tn * (K >> 5) + tkk) * 4096;
        #pragma unroll
        for (int s = 0; s < 2; ++s)
            #pragma unroll
            for (int kh = 0; kh < 2; ++kh) {
                half8 h;
                #pragma unroll
                for (int j = 0; j < 8; ++j)
                    h[j] = (_Float16)tile[hf * 32 + s * 16 + kh * 8 + j][c];
                *(half8*)(T + base + (size_t)((s * 2 + kh) * 128 + c) * 8) = h;
            }
    }
}

// feats[b] [196][2048] f32 -> FT[b] tiled f16 image, in TWO 32-row passes
// so the LDS tile is only [32][129] f32 (16.5 KB). Pass p == old hf=p half.
__device__ inline void prep_bT32(
    const float* __restrict__ Wb, _Float16* __restrict__ T,
    int tn, int tk, int t, float (*tile)[129])
{
    #pragma unroll
    for (int p = 0; p < 2; ++p) {
        if (p) __syncthreads();             // tile reuse hazard
        {
            const int kr = t >> 3;          // 0..31
            const int nc = (t & 7) * 16;    // 0..112
            const int gn = tk * 64 + p * 32 + kr;
            #pragma unroll
            for (int q = 0; q < 4; ++q) {
                float4v v = {0.f, 0.f, 0.f, 0.f};
                if (gn < NKEY)
                    v = *(const float4v*)(Wb + (size_t)gn * ATT_FEAT + tn * 128 + nc + q * 4);
                tile[kr][nc + q*4 + 0] = v.x; tile[kr][nc + q*4 + 1] = v.y;
                tile[kr][nc + q*4 + 2] = v.z; tile[kr][nc + q*4 + 3] = v.w;
            }
        }
        __syncthreads();
        {
            const int c = t & 127;          // f-row 0..127
            const int s = t >> 7;           // 0/1
            const int tkk = tk * 2 + p;     // valid 0..6
            if (tkk < 7) {
                const size_t base = ((size_t)tn * 7 + tkk) * 4096;
                #pragma unroll
                for (int kh = 0; kh < 2; ++kh) {
                    half8 h;
                    #pragma unroll
                    for (int j = 0; j < 8; ++j)
                        h[j] = (_Float16)tile[s * 16 + kh * 8 + j][c];
                    *(half8*)(T + base + (size_t)((s * 2 + kh) * 128 + c) * 8) = h;
                }
            }
        }
    }
}

__global__ __launch_bounds__(256) void uber_prep(
    const float* __restrict__ hidden, const float* __restrict__ feats,
    const float* __restrict__ w_h, const float* __restrict__ w_u,
    _Float16* HA, _Float16* FA, _Float16* HB, _Float16* UB)
{
    __shared__ float tile[64][129];
    const int id = blockIdx.x;
    const int t  = threadIdx.x;
    if (id < 128) {
        prep_a128(hidden, HA, HIDDEN, BATCH * SEQ, id >> 4, id & 15, t);
    } else if (id < 928) {
        const int j = id - 128;
        prep_a128(feats, FA, ATT_FEAT, BATCH * NKEY, j >> 5, j & 31, t);
    } else if (id < 992) {
        const int j = id - 928;
        prep_b128(w_h, HB, HIDDEN, EMBED, j >> 4, j & 15, t, tile);
    } else {
        const int j = id - 992;
        prep_b128(w_u, UB, ATT_FEAT, EMBED, j >> 5, j & 31, t, tile);
    }
}

// ---------------------------------------------------------------------------
// uber GEMM f16 (k-split): 128x128 tile, 4 waves 2x2, wave 64x64, BK=32,
// 16 k-steps/block. 3-deep LDS buffers (48 KB), counted vmcnt(4).
// Partials f16, KC-scaled, bias in partial 0. Grid 464 = 8*58 XCD swizzle.
// ---------------------------------------------------------------------------
__global__ __launch_bounds__(256) void uber_gemm(
    const _Float16* __restrict__ HA, const _Float16* __restrict__ HB,
    const _Float16* __restrict__ FA, const _Float16* __restrict__ UB,
    const float* __restrict__ bvec, _Float16* __restrict__ WhP,
    _Float16* __restrict__ UvP)
{
    __shared__ __align__(16) _Float16 L[2][3][4096];   // 48 KB

    const int hh = blockIdx.x;
    const int t0 = (hh & 7) * 58 + (hh >> 3);          // bijective, G=464

    const _Float16 *Aimg, *Bimg;
    const float* bias = nullptr;
    _Float16* C;
    int rt, ct, tk0, aK;
    if (t0 < 400) {            // K2: Uv partials
        const int ks = t0 / 100, rem = t0 % 100;
        rt = rem >> 2; ct = rem & 3;
        Aimg = FA; Bimg = UB;
        aK = ATT_FEAT >> 5; tk0 = ks * 16;
        C = UvP + (size_t)ks * MPAD * EMBED;
        if (ks == 0) bias = bvec;
    } else {                   // K1: Wh partials
        const int v = t0 - 400;
        const int ks = v >> 5, rem = v & 31;
        rt = rem >> 2; ct = rem & 3;
        Aimg = HA; Bimg = HB;
        aK = HIDDEN >> 5; tk0 = ks * 16;
        C = WhP + (size_t)ks * (BATCH * SEQ) * EMBED;
    }

    const int tid = threadIdx.x, lane = tid & 63, w = tid >> 6;
    const int wr = w >> 1, wc = w & 1;
    const int l31 = lane & 31, kh = lane >> 5;

    const int isB = w >> 1;
    const int whf = w & 1;
    const _Float16* srcMat = isB ? Bimg : Aimg;
    const int majorTile = isB ? ct : rt;
    const _Float16* src0 =
        srcMat + ((size_t)majorTile * aK + tk0) * 4096 + whf * 2048 + lane * 8;

    f32x16 acc[2][2] = {};

    auto stage = [&](int buf, int t) {
        const _Float16* s = src0 + (size_t)t * 4096;
        _Float16* d = &L[isB][buf][0] + whf * 2048 + lane * 8;
        #pragma unroll
        for (int c = 0; c < 4; ++c)
            gl_lds16(s + c * 512, d + c * 512);
    };

    auto compute = [&](int buf) {
        #pragma unroll
        for (int s = 0; s < 2; ++s) {
            const int rb = (s * 2 + kh) * 128;
            half8 a[2], b[2];
            #pragma unroll
            for (int m = 0; m < 2; ++m)
                a[m] = *(const half8*)&L[0][buf][(rb + wr * 64 + m * 32 + l31) * 8];
            #pragma unroll
            for (int n = 0; n < 2; ++n)
                b[n] = *(const half8*)&L[1][buf][(rb + wc * 64 + n * 32 + l31) * 8];
            __builtin_amdgcn_s_setprio(1);
            #pragma unroll
            for (int m = 0; m < 2; ++m)
                #pragma unroll
                for (int n = 0; n < 2; ++n)
                    acc[m][n] = __builtin_amdgcn_mfma_f32_32x32x16_f16(a[m], b[n], acc[m][n], 0, 0, 0);
            __builtin_amdgcn_s_setprio(0);
        }
    };

    stage(0, 0); stage(1, 1);              // prefetch depth 2
    int cur = 0, nxt = 2;
    #pragma unroll 1
    for (int t = 0; t < 16; ++t) {
        if (t + 1 < 16) asm volatile("s_waitcnt vmcnt(4)" ::: "memory");
        else            asm volatile("s_waitcnt vmcnt(0)" ::: "memory");
        __builtin_amdgcn_s_barrier();
        if (t + 2 < 16) stage(nxt, t + 2);
        __builtin_amdgcn_sched_barrier(0);
        compute(cur);
        __builtin_amdgcn_sched_barrier(0);
        cur = (cur == 2) ? 0 : cur + 1;
        nxt = (nxt == 2) ? 0 : nxt + 1;
    }

    // epilogue: col=lane&31, row=(r&3)+8*(r>>2)+4*kh; scale KC, store f16
    #pragma unroll
    for (int m = 0; m < 2; ++m) {
        const int row0 = rt * 128 + wr * 64 + m * 32;
        #pragma unroll
        for (int n = 0; n < 2; ++n) {
            const int colg = ct * 128 + wc * 64 + n * 32 + l31;
            const float bv = bias ? bias[colg] : 0.f;
            #pragma unroll
            for (int r = 0; r < 16; ++r) {
                const int row = (r & 3) + 8 * (r >> 2) + 4 * kh;
                C[(size_t)(row0 + row) * EMBED + colg] =
                    (_Float16)((acc[m][n][r] + bv) * KCONST);
            }
        }
    }
}

// ---------------------------------------------------------------------------
// scores + FT prep merged: ids [0,832) = scores units; [832,1856) = FT units.
// LDS union now only 20.5 KB (FT uses the 2-pass 32-row tile).
// ---------------------------------------------------------------------------
__global__ __launch_bounds__(256) void scores_ft(
    const _Float16* __restrict__ WhP, const _Float16* __restrict__ UvP,
    const float* __restrict__ wvec, const float* __restrict__ feats,
    float* __restrict__ scr4, _Float16* __restrict__ FT)
{
    __shared__ __align__(16) char smem[20480];   // max(scores 20 KB, FT 16.5 KB)
    const int id = blockIdx.x;
    const int tid = threadIdx.x;

    if (id >= 832) {                       // ---- FT prep unit ----
        const int j = id - 832;
        const int b = j >> 6, rem = j & 63;
        prep_bT32(feats + (size_t)b * NKEY * ATT_FEAT,
                  FT + (size_t)b * 16 * 7 * 4096, rem >> 2, rem & 3, tid,
                  (float(*)[129])smem);
        return;
    }

    // ---- scores unit ----
    const int n0 = (id % 13) * 16;
    const int eq = (id / 13) & 3;
    const int b  = id / 52;
    const int w    = tid >> 6;
    const int lane = tid & 63;         // = s

    float* whs = (float*)smem;                          // 16 KB, swizzled
    float (*uvs)[64] = (float(*)[64])(smem + 16384);    // 4 KB

    const size_t WHS = (size_t)(BATCH * SEQ) * EMBED;
    const size_t UVS = (size_t)MPAD * EMBED;

    float acc[4] = {};
    char* whsB = (char*)whs;

    for (int ch = 0; ch < 2; ++ch) {
        const int e0 = eq * 128 + ch * 64;
        {
            const int r = tid >> 2;
            const _Float16* Wr = WhP + (size_t)(b * SEQ + r) * EMBED + e0 + (tid & 3) * 16;
            half8 h0 = *(const half8*)(Wr);
            half8 h1 = *(const half8*)(Wr + 8);
            half8 g0 = *(const half8*)(Wr + WHS);
            half8 g1 = *(const half8*)(Wr + WHS + 8);
            float f[16];
            #pragma unroll
            for (int j = 0; j < 8; ++j) {
                f[j]     = (float)h0[j] + (float)g0[j];
                f[8 + j] = (float)h1[j] + (float)g1[j];
            }
            #pragma unroll
            for (int q = 0; q < 4; ++q) {
                const int cc = (tid & 3) * 16 + q * 4;
                float4v v = { f[q*4+0], f[q*4+1], f[q*4+2], f[q*4+3] };
                *(float4v*)(whsB + r * 256 + ((cc * 4) ^ ((r & 15) << 4))) = v;
            }
        }
        {
            const int nl = tid >> 4;
            const int c4 = tid & 15;
            const int nr = (n0 + nl < NKEY) ? (n0 + nl) : (NKEY - 1);
            const _Float16* Ur = UvP + (size_t)(b * NKEY + nr) * EMBED + e0 + c4 * 4;
            half4 u0 = *(const half4*)(Ur);
            half4 u1 = *(const half4*)(Ur + UVS);
            half4 u2 = *(const half4*)(Ur + 2 * UVS);
            half4 u3 = *(const half4*)(Ur + 3 * UVS);
            float4v u;
            u.x = ((float)u0[0] + (float)u1[0]) + ((float)u2[0] + (float)u3[0]);
            u.y = ((float)u0[1] + (float)u1[1]) + ((float)u2[1] + (float)u3[1]);
            u.z = ((float)u0[2] + (float)u1[2]) + ((float)u2[2] + (float)u3[2]);
            u.w = ((float)u0[3] + (float)u1[3]) + ((float)u2[3] + (float)u3[3]);
            *(float4v*)&uvs[nl][c4 * 4] = u;
        }
        __syncthreads();

        #pragma unroll
        for (int ec = 0; ec < 8; ++ec) {
            const int sb = lane * 256;
            float4v wh0 = *(const float4v*)(whsB + sb + ((ec * 32 +  0) ^ ((lane & 15) << 4)));
            float4v wh1 = *(const float4v*)(whsB + sb + ((ec * 32 + 16) ^ ((lane & 15) << 4)));
            float wf[8];
            #pragma unroll
            for (int i = 0; i < 8; ++i) wf[i] = wvec[e0 + ec * 8 + i];
            #pragma unroll
            for (int j = 0; j < 4; ++j) {
                const int nl = w * 4 + j;
                float4v u0 = *(const float4v*)&uvs[nl][ec * 8];
                float4v u1 = *(const float4v*)&uvs[nl][ec * 8 + 4];
                float t0 = __builtin_amdgcn_exp2f(wh0.x + u0.x);
                float t1 = __builtin_amdgcn_exp2f(wh0.y + u0.y);
                float t2 = __builtin_amdgcn_exp2f(wh0.z + u0.z);
                float t3 = __builtin_amdgcn_exp2f(wh0.w + u0.w);
                float t4 = __builtin_amdgcn_exp2f(wh1.x + u1.x);
                float t5 = __builtin_amdgcn_exp2f(wh1.y + u1.y);
                float t6 = __builtin_amdgcn_exp2f(wh1.z + u1.z);
                float t7 = __builtin_amdgcn_exp2f(wh1.w + u1.w);
                float a = acc[j];
                a = fmaf(wf[0], __builtin_amdgcn_rcpf(1.f + t0), a);
                a = fmaf(wf[1], __builtin_amdgcn_rcpf(1.f + t1), a);
                a = fmaf(wf[2], __builtin_amdgcn_rcpf(1.f + t2), a);
                a = fmaf(wf[3], __builtin_amdgcn_rcpf(1.f + t3), a);
                a = fmaf(wf[4], __builtin_amdgcn_rcpf(1.f + t4), a);
                a = fmaf(wf[5], __builtin_amdgcn_rcpf(1.f + t5), a);
                a = fmaf(wf[6], __builtin_amdgcn_rcpf(1.f + t6), a);
                a = fmaf(wf[7], __builtin_amdgcn_rcpf(1.f + t7), a);
                acc[j] = a;
            }
        }
        __syncthreads();
    }

    float* dst = scr4 + ((size_t)eq * (BATCH * SEQ) + b * SEQ + lane) * NKEY;
    #pragma unroll
    for (int j = 0; j < 4; ++j) {
        const int n = n0 + w * 4 + j;
        if (n < NKEY) dst[n] = 2.f * acc[j];
    }
}

// ---------------------------------------------------------------------------
// attn MFMA: block = one b x 128 f x all 64 s. Grid (16 fb, 16 b).
// ---------------------------------------------------------------------------
__global__ __launch_bounds__(256) void attn_mfma(
    const float* __restrict__ scr4, const int* __restrict__ mask,
    const _Float16* __restrict__ FT,
    float* __restrict__ weights_out, float* __restrict__ out)
{
    const int fb = blockIdx.x;
    const int b  = blockIdx.y;
    const int t  = threadIdx.x;
    const int lane = t & 63, w = t >> 6;
    const int wr = w >> 1, wc = w & 1;          // wave: 32 s x 64 f
    const int l31 = lane & 31, khl = lane >> 5;

    __shared__ __align__(16) _Float16 wtL[7 * 4 * 64 * 8];   // 28 KB
    __shared__ __align__(16) _Float16 Lb[3][4096];           // 24 KB

    const _Float16* FTb = FT + (size_t)b * 16 * 7 * 4096 + (size_t)fb * 7 * 4096;

    auto stage = [&](int buf, int kt) {
        const _Float16* s = FTb + (size_t)kt * 4096 + w * 1024 + lane * 8;
        _Float16* d = &Lb[buf][0] + w * 1024 + lane * 8;
        gl_lds16(s, d);
        gl_lds16(s + 512, d + 512);
    };

    stage(0, 0); stage(1, 1);

    // ---- zero wtL (covers n in [196,224)) ----
    #pragma unroll
    for (int i = 0; i < 7; ++i)
        *(half8*)&wtL[(i * 256 + t) * 8] = (half8)(_Float16)0.f;

    asm volatile("s_waitcnt lgkmcnt(0)" ::: "memory");
    __builtin_amdgcn_s_barrier();

    // ---- softmax: row r = t>>2 (64 rows), quad lanes ln = t&3 ----
    {
        const int r  = t >> 2;
        const int ln = t & 3;
        const size_t SCRS = (size_t)(BATCH * SEQ) * NKEY;
        const float* p = scr4 + (size_t)(b * SEQ + r) * NKEY;
        const int* mrow = mask + b * NKEY;
        float v[49];
        float mx = -INFINITY;
        #pragma unroll
        for (int j = 0; j < 49; ++j) {
            const int n = ln + 4 * j;
            float s = (p[n] + p[SCRS + n]) + (p[2 * SCRS + n] + p[3 * SCRS + n]);
            if (mrow[n] == 0) s = -1e9f;
            v[j] = s;
            mx = fmaxf(mx, s);
        }
        mx = fmaxf(mx, __shfl_xor(mx, 1));
        mx = fmaxf(mx, __shfl_xor(mx, 2));
        float sum = 0.f;
        #pragma unroll
        for (int j = 0; j < 49; ++j) {
            v[j] = __builtin_amdgcn_exp2f((v[j] - mx) * LOG2E);
            sum += v[j];
        }
        sum += __shfl_xor(sum, 1);
        sum += __shfl_xor(sum, 2);
        const float inv = __builtin_amdgcn_rcpf(sum);
        float* wrow = weights_out + (size_t)(b * SEQ + r) * NKEY;
        #pragma unroll
        for (int j = 0; j < 49; ++j) {
            const int n = ln + 4 * j;
            const float wv = v[j] * inv;
            if (fb == 0) wrow[n] = wv;
            const int grp = ((n >> 4) & 1) * 2 + ((n >> 3) & 1);
            wtL[(((n >> 5) * 4 + grp) * 64 + r) * 8 + (n & 7)] = (_Float16)wv;
        }
    }
    asm volatile("s_waitcnt lgkmcnt(0)" ::: "memory");

    // ---- MFMA k-loop: 7 steps of 32 n ----
    f32x16 acc[2] = {};
    #pragma unroll 1
    for (int kt = 0; kt < 7; ++kt) {
        if (kt < 6) asm volatile("s_waitcnt vmcnt(2)" ::: "memory");
        else        asm volatile("s_waitcnt vmcnt(0)" ::: "memory");
        __builtin_amdgcn_s_barrier();
        if (kt + 2 < 7) stage((kt + 2) % 3, kt + 2);
        __builtin_amdgcn_sched_barrier(0);
        const int buf = kt % 3;
        #pragma unroll
        for (int ks = 0; ks < 2; ++ks) {
            half8 a = *(const half8*)&wtL[(((kt * 4) + ks * 2 + khl) * 64 + wr * 32 + l31) * 8];
            half8 b0 = *(const half8*)&Lb[buf][((ks * 2 + khl) * 128 + wc * 64 + l31) * 8];
            half8 b1 = *(const half8*)&Lb[buf][((ks * 2 + khl) * 128 + wc * 64 + 32 + l31) * 8];
            acc[0] = __builtin_amdgcn_mfma_f32_32x32x16_f16(a, b0, acc[0], 0, 0, 0);
            acc[1] = __builtin_amdgcn_mfma_f32_32x32x16_f16(a, b1, acc[1], 0, 0, 0);
        }
        __builtin_amdgcn_sched_barrier(0);
    }

    // ---- epilogue: C[s, f] ----
    #pragma unroll
    for (int nf = 0; nf < 2; ++nf) {
        const int f = fb * 128 + wc * 64 + nf * 32 + l31;
        #pragma unroll
        for (int r = 0; r < 16; ++r) {
            const int srow = wr * 32 + (r & 3) + 8 * (r >> 2) + 4 * khl;
            out[(size_t)(b * SEQ + srow) * ATT_FEAT + f] = acc[nf][r];
        }
    }
}

// ---------------------------------------------------------------------------
extern "C" void kernel_launch(void* const* d_in, const int* in_sizes, int n_in,
                              void* d_out, int out_size, void* d_ws, size_t ws_size,
                              hipStream_t stream)
{
    const float* hidden = (const float*)d_in[0];
    const float* feats  = (const float*)d_in[1];
    const int*   mask   = (const int*)  d_in[2];
    const float* w_h    = (const float*)d_in[3];
    const float* w_u    = (const float*)d_in[4];
    const float* bvec   = (const float*)d_in[5];
    const float* wvec   = (const float*)d_in[6];

    float* out         = (float*)d_out;
    float* attn_out    = out;
    float* weights_out = out + (size_t)BATCH * SEQ * ATT_FEAT;

    // workspace layout (~52 MB)
    _Float16* WhP = (_Float16*)d_ws;                             // 2 x 1024x512 f16
    _Float16* UvP = WhP + (size_t)2 * BATCH * SEQ * EMBED;       // 4 x 3200x512 f16
    float*    scr4 = (float*)(UvP + (size_t)4 * MPAD * EMBED);   // 4 x 1024x196 f32
    _Float16* FA = (_Float16*)(scr4 + (size_t)4 * BATCH * SEQ * NKEY);
    _Float16* HA = FA + (size_t)MPAD * ATT_FEAT;
    _Float16* UB = HA + (size_t)BATCH * SEQ * HIDDEN;
    _Float16* HB = UB + (size_t)EMBED * ATT_FEAT;
    _Float16* FT = HB + (size_t)EMBED * HIDDEN;                  // 16b x 16tn x 7 x 4096

    // 1) GEMM-image preps (1120 blocks)
    uber_prep<<<dim3(1120), 256, 0, stream>>>(
        hidden, feats, w_h, w_u, HA, FA, HB, UB);

    // 2) both GEMMs k-split (464 blocks), f16 product, f16 partials, KC-scaled
    uber_gemm<<<dim3(464), 256, 0, stream>>>(
        HA, HB, FA, UB, bvec, WhP, UvP);

    // 3) partial scores (832 units) + FT transpose prep (1024 units) co-run
    scores_ft<<<dim3(1856), 256, 0, stream>>>(
        WhP, UvP, wvec, feats, scr4, FT);

    // 4) softmax + weights write + MFMA attn
    attn_mfma<<<dim3(16, 16), 256, 0, stream>>>(
        scr4, mask, FT, weights_out, attn_out);
}